// Round 1
// baseline (358.104 us; speedup 1.0000x reference)
//
#include <hip/hip_runtime.h>

// Problem constants (from reference): B=4, K=16, H=480, W=640, P=200000, C=3
constexpr int B_ = 4, K_ = 16, H_ = 480, W_ = 640, P_ = 200000;
constexpr int HW   = H_ * W_;     // 307200 pixels per (b,k) plane
constexpr int PIX4 = HW / 4;      // 76800 int4-groups per plane

__global__ __launch_bounds__(256) void compositor_kernel(
    const int*   __restrict__ frag,    // (B,K,H,W) int32
    const float* __restrict__ alpha,   // (B,K,H,W) f32
    const float* __restrict__ ptclds,  // (C,P) f32
    const float* __restrict__ im,      // (C,H,W) f32
    float*       __restrict__ out)     // (B,C,H,W) f32
{
    const int t = blockIdx.x * blockDim.x + threadIdx.x;   // [0, B_*PIX4)
    const int b = t / PIX4;
    const int g = t - b * PIX4;
    const int p = g * 4;                                   // first pixel of this group

    const int4*   fb = (const int4*)  (frag  + (size_t)b * K_ * HW + p);
    const float4* ab = (const float4*)(alpha + (size_t)b * K_ * HW + p);

    float T[4]      = {1.f, 1.f, 1.f, 1.f};
    float acc[3][4] = {{0.f,0.f,0.f,0.f},{0.f,0.f,0.f,0.f},{0.f,0.f,0.f,0.f}};

    int f0[4]; // k=0 fragments, for background test
    {
        int4 v = fb[0];
        f0[0] = v.x; f0[1] = v.y; f0[2] = v.z; f0[3] = v.w;
    }

    #pragma unroll
    for (int k = 0; k < K_; ++k) {
        int4   fv = fb[(size_t)k * PIX4];
        float4 av = ab[(size_t)k * PIX4];
        int   fi[4] = {fv.x, fv.y, fv.z, fv.w};
        float ai[4] = {av.x, av.y, av.z, av.w};

        #pragma unroll
        for (int j = 0; j < 4; ++j) {
            const bool valid = fi[j] >= 0;
            const float a = valid ? ai[j] : 0.0f;
            const float w = a * T[j];          // a * exclusive cumprod(1-a)
            T[j] *= (1.0f - a);
            const int idx = valid ? fi[j] : 0; // clip(frag, 0)
            acc[0][j] += w * ptclds[idx];
            acc[1][j] += w * ptclds[P_   + idx];
            acc[2][j] += w * ptclds[2*P_ + idx];
        }
    }

    // Background override (frag[b,0,h,w] < 0 -> im), then coalesced float4 store
    #pragma unroll
    for (int c = 0; c < 3; ++c) {
        float o[4];
        #pragma unroll
        for (int j = 0; j < 4; ++j) {
            o[j] = (f0[j] < 0) ? im[(size_t)c * HW + p + j] : acc[c][j];
        }
        float4 v = make_float4(o[0], o[1], o[2], o[3]);
        *(float4*)(out + ((size_t)b * 3 + c) * HW + p) = v;
    }
}

extern "C" void kernel_launch(void* const* d_in, const int* in_sizes, int n_in,
                              void* d_out, int out_size, void* d_ws, size_t ws_size,
                              hipStream_t stream) {
    const int*   frag   = (const int*)  d_in[0];
    const float* alpha  = (const float*)d_in[1];
    const float* ptclds = (const float*)d_in[2];
    const float* im     = (const float*)d_in[3];
    float*       out    = (float*)d_out;

    const int total_threads = B_ * PIX4;   // 307200
    compositor_kernel<<<total_threads / 256, 256, 0, stream>>>(
        frag, alpha, ptclds, im, out);
}